// Round 6
// baseline (198.168 us; speedup 1.0000x reference)
//
#include <hip/hip_runtime.h>
#include <hip/hip_bf16.h>

typedef unsigned char u8;
typedef unsigned int u32;
typedef float f32x16 __attribute__((ext_vector_type(16)));
typedef int i32x4 __attribute__((ext_vector_type(4)));
typedef int i32x8 __attribute__((ext_vector_type(8)));

#define B_SZ 8192
#define D_SZ 768
#define TAU_INV 10.0f
// values scaled by 16 -> logits scaled by 256; exp2 constant = log2(e)*10/256
#define ESCALE 0.05635527503472513f
#define FP8_SCALE 16.0f

__device__ __forceinline__ void gld_lds16(const u8* g, u8* l) {
    __builtin_amdgcn_global_load_lds((const __attribute__((address_space(1))) void*)g,
                                     (__attribute__((address_space(3))) void*)l,
                                     16, 0, 0);
}

// HW packed fp32->fp8(e4m3) conversion: v_cvt_pk_fp8_f32, 2 floats per instr
__device__ __forceinline__ u32 pack_fp8x4(float x, float y, float z, float w) {
    int p = __builtin_amdgcn_cvt_pk_fp8_f32(x, y, 0, false);   // low word
    p = __builtin_amdgcn_cvt_pk_fp8_f32(z, w, p, true);        // high word
    return (u32)p;
}

// ---------------- Kernel 1: row norms, fp8 normalize (x16), fp32 diag ----------------
__global__ __launch_bounds__(256) void norm_kernel(const float4* __restrict__ v,
                                                   const float4* __restrict__ u,
                                                   u32* __restrict__ vn,
                                                   u32* __restrict__ un,
                                                   float* __restrict__ diag) {
    const int wid = threadIdx.x >> 6, lane = threadIdx.x & 63;
    const int row = blockIdx.x * 4 + wid;
    const float4* vr = v + (size_t)row * 192;
    const float4* ur = u + (size_t)row * 192;
    float4 a[3], b[3];
    float sv = 0.f, su = 0.f, sd = 0.f;
#pragma unroll
    for (int c = 0; c < 3; ++c) {
        a[c] = vr[lane + 64 * c];
        b[c] = ur[lane + 64 * c];
        sv += a[c].x * a[c].x + a[c].y * a[c].y + a[c].z * a[c].z + a[c].w * a[c].w;
        su += b[c].x * b[c].x + b[c].y * b[c].y + b[c].z * b[c].z + b[c].w * b[c].w;
        sd += a[c].x * b[c].x + a[c].y * b[c].y + a[c].z * b[c].z + a[c].w * b[c].w;
    }
#pragma unroll
    for (int m = 1; m < 64; m <<= 1) {
        sv += __shfl_xor(sv, m);
        su += __shfl_xor(su, m);
        sd += __shfl_xor(sd, m);
    }
    const float iv = FP8_SCALE / fmaxf(sqrtf(sv), 1e-8f);
    const float iu = FP8_SCALE / fmaxf(sqrtf(su), 1e-8f);
#pragma unroll
    for (int c = 0; c < 3; ++c) {
        vn[(size_t)row * 192 + lane + 64 * c] =
            pack_fp8x4(a[c].x * iv, a[c].y * iv, a[c].z * iv, a[c].w * iv);
        un[(size_t)row * 192 + lane + 64 * c] =
            pack_fp8x4(b[c].x * iu, b[c].y * iu, b[c].z * iu, b[c].w * iu);
    }
    if (lane == 0) diag[row] = sd * iv * iu * TAU_INV / (FP8_SCALE * FP8_SCALE);
}

// ------- Kernel 2: 128x128 fp8 MX MFMA tile (BK=64). A staged in LDS (XOR-swizzled,
//         1-barrier dbuf); B fragments loaded DIRECTLY from global (L2-resident) -------
__global__ __launch_bounds__(256, 4) void simexp_kernel(const u8* __restrict__ vn,
                                                        const u8* __restrict__ un,
                                                        float* __restrict__ rowP,
                                                        float* __restrict__ colP) {
    // smem: As buf0 [0,8K), As buf1 [8K,16K). Epilogue scratch aliases buf0.
    __shared__ __align__(64) u8 smem[16384];
    u8* As = smem;

    const int tid  = threadIdx.x;
    const int wid  = tid >> 6;
    const int lane = tid & 63;
    const int l32  = lane & 31;
    const int h    = lane >> 5;
    const int wr = wid >> 1, wc = wid & 1;

    // 8x8 chunked grid for L2 locality
    const int id = blockIdx.x;
    const int chunk = id >> 6;
    const int li = id & 63;
    const int rb = ((chunk >> 3) << 3) + (li >> 3);
    const int cb = ((chunk & 7) << 3) + (li & 7);

    // A staging lane map: row sr = lane>>2, LDS chunk c = lane&3, global chunk = c ^ ((sr>>1)&3)
    const int sr = lane >> 2;
    const int sc = (((lane & 3) ^ ((lane >> 3) & 3)) << 4);
    const u8* Ag0 = vn + (size_t)(rb * 128 + wid * 32 + sr) * D_SZ + sc;
    const size_t rstep = (size_t)16 * D_SZ;
    u8* AsW = As + (wid * 32) * 64;   // wave-uniform LDS base (buf 0)

    // B direct-load base: lane reads row cb*128 + wc*64 + (j*32) + l32, bytes [k0+32h, +32)
    const u8* Bg = un + (size_t)(cb * 128 + wc * 64 + l32) * D_SZ + h * 32;
    const size_t jstep = (size_t)32 * D_SZ;

    f32x16 acc[2][2];
#pragma unroll
    for (int i = 0; i < 2; ++i)
#pragma unroll
        for (int j = 0; j < 2; ++j)
#pragma unroll
            for (int r = 0; r < 16; ++r) acc[i][j][r] = 0.f;

    // prologue: stage A tile 0 into buffer 0
    gld_lds16(Ag0, AsW);
    gld_lds16(Ag0 + rstep, AsW + 16 * 64);

    const int s4 = (l32 >> 1) & 3;
    const int loA = ((2 * h) ^ s4) << 4;       // lo-chunk byte offset within row
    const int hiA = ((2 * h + 1) ^ s4) << 4;
    const int aOff = (wr * 64 + l32) * 64;     // base LDS offset (buf-relative)

    for (int it = 0; it < 12; ++it) {
        __syncthreads();   // A staging of buf[it&1] complete; prior reads of other buf done
        const int cur = (it & 1) * 8192;
        const int k0 = it * 64;
        if (it + 1 < 12) {
            const int nxt = ((it + 1) & 1) * 8192;
            gld_lds16(Ag0 + k0 + 64, AsW + nxt);
            gld_lds16(Ag0 + rstep + k0 + 64, AsW + nxt + 16 * 64);
        }
        // B fragment loads (L2): issue all four early so latency overlaps ds_reads
        i32x4 b0l = *(const i32x4*)(Bg + k0);
        i32x4 b0h = *(const i32x4*)(Bg + k0 + 16);
        i32x4 b1l = *(const i32x4*)(Bg + jstep + k0);
        i32x4 b1h = *(const i32x4*)(Bg + jstep + k0 + 16);
        // A fragments from LDS
        i32x8 af[2];
#pragma unroll
        for (int i = 0; i < 2; ++i) {
            const u8* arow = As + cur + aOff + i * 2048;
            i32x4 lo = *(const i32x4*)(arow + loA);
            i32x4 hi = *(const i32x4*)(arow + hiA);
            af[i] = __builtin_shufflevector(lo, hi, 0, 1, 2, 3, 4, 5, 6, 7);
        }
        i32x8 bf0 = __builtin_shufflevector(b0l, b0h, 0, 1, 2, 3, 4, 5, 6, 7);
        acc[0][0] = __builtin_amdgcn_mfma_scale_f32_32x32x64_f8f6f4(
            af[0], bf0, acc[0][0], 0, 0, 0, 0x7F7F7F7F, 0, 0x7F7F7F7F);
        acc[1][0] = __builtin_amdgcn_mfma_scale_f32_32x32x64_f8f6f4(
            af[1], bf0, acc[1][0], 0, 0, 0, 0x7F7F7F7F, 0, 0x7F7F7F7F);
        i32x8 bf1 = __builtin_shufflevector(b1l, b1h, 0, 1, 2, 3, 4, 5, 6, 7);
        acc[0][1] = __builtin_amdgcn_mfma_scale_f32_32x32x64_f8f6f4(
            af[0], bf1, acc[0][1], 0, 0, 0, 0x7F7F7F7F, 0, 0x7F7F7F7F);
        acc[1][1] = __builtin_amdgcn_mfma_scale_f32_32x32x64_f8f6f4(
            af[1], bf1, acc[1][1], 0, 0, 0, 0x7F7F7F7F, 0, 0x7F7F7F7F);
    }

    // Epilogue. 32x32 C/D layout: col = lane&31, row = (reg&3) + 8*(reg>>2) + 4*h
    float rowAcc[32];   // [i*16 + reg]
    float colAcc[2];    // [j]
#pragma unroll
    for (int t = 0; t < 32; ++t) rowAcc[t] = 0.f;
    colAcc[0] = 0.f; colAcc[1] = 0.f;
#pragma unroll
    for (int i = 0; i < 2; ++i)
#pragma unroll
        for (int j = 0; j < 2; ++j)
#pragma unroll
            for (int r = 0; r < 16; ++r) {
                float e = exp2f(acc[i][j][r] * ESCALE);
                rowAcc[i * 16 + r] += e;
                colAcc[j] += e;
            }
    // row sums: reduce across the 32 cols (lanes with same h)
#pragma unroll
    for (int m = 1; m < 32; m <<= 1)
#pragma unroll
        for (int t = 0; t < 32; ++t) rowAcc[t] += __shfl_xor(rowAcc[t], m);
    // col sums: add the other h half (rows)
    colAcc[0] += __shfl_xor(colAcc[0], 32);
    colAcc[1] += __shfl_xor(colAcc[1], 32);

    __syncthreads();  // all K-loop LDS traffic done; staging buffer is now dead
    float (*rowLds)[128] = (float (*)[128])(smem);          // [2][128]
    float (*colLds)[128] = (float (*)[128])(smem + 1024);   // [2][128]
#pragma unroll
    for (int i = 0; i < 2; ++i)
#pragma unroll
        for (int t = 0; t < 16; ++t)
            if (l32 == t) {
                int row = wr * 64 + i * 32 + (t & 3) + 8 * (t >> 2) + 4 * h;
                rowLds[wc][row] = rowAcc[i * 16 + t];
            }
    if (h == 0) {
#pragma unroll
        for (int j = 0; j < 2; ++j)
            colLds[wr][wc * 64 + j * 32 + l32] = colAcc[j];
    }
    __syncthreads();
    if (tid < 128) {
        rowP[(size_t)cb * B_SZ + rb * 128 + tid] = rowLds[0][tid] + rowLds[1][tid];
    } else {
        const int t = tid - 128;
        colP[(size_t)rb * B_SZ + cb * 128 + t] = colLds[0][t] + colLds[1][t];
    }
}

// ---------------- Kernel 3: reduce partials, log, subtract diag, mean ----------------
__global__ __launch_bounds__(256) void finalize_kernel(const float* __restrict__ rowP,
                                                       const float* __restrict__ colP,
                                                       const float* __restrict__ diag,
                                                       float* __restrict__ out) {
    const int i = blockIdx.x * 256 + threadIdx.x;
    float rs = 0.f, cs = 0.f;
#pragma unroll 8
    for (int p = 0; p < 64; ++p) {
        rs += rowP[(size_t)p * B_SZ + i];
        cs += colP[(size_t)p * B_SZ + i];
    }
    float contrib = (0.75f * logf(rs) + 0.25f * logf(cs) - diag[i]) * (1.0f / (float)B_SZ);
#pragma unroll
    for (int m = 1; m < 64; m <<= 1) contrib += __shfl_xor(contrib, m);
    __shared__ float red[4];
    const int wid = threadIdx.x >> 6, lane = threadIdx.x & 63;
    if (lane == 0) red[wid] = contrib;
    __syncthreads();
    if (threadIdx.x == 0) atomicAdd(out, red[0] + red[1] + red[2] + red[3]);
}

extern "C" void kernel_launch(void* const* d_in, const int* in_sizes, int n_in,
                              void* d_out, int out_size, void* d_ws, size_t ws_size,
                              hipStream_t stream) {
    const float* v = (const float*)d_in[0];
    const float* u = (const float*)d_in[1];
    char* ws = (char*)d_ws;
    // workspace layout (~16.7 MB)
    u8* vn8    = (u8*)(ws);                     // 8192*768    = 6,291,456
    u8* un8    = (u8*)(ws + 6291456);           // 6,291,456
    float* dg  = (float*)(ws + 12582912);       // 8192*4      = 32,768
    float* rwp = (float*)(ws + 12615680);       // 64*8192*4   = 2,097,152
    float* clp = (float*)(ws + 14712832);       // 2,097,152
    float* out = (float*)d_out;

    hipMemsetAsync(out, 0, sizeof(float), stream);
    hipLaunchKernelGGL(norm_kernel, dim3(2048), dim3(256), 0, stream,
                       (const float4*)v, (const float4*)u, (u32*)vn8, (u32*)un8, dg);
    hipLaunchKernelGGL(simexp_kernel, dim3(4096), dim3(256), 0, stream, vn8, un8, rwp, clp);
    hipLaunchKernelGGL(finalize_kernel, dim3(B_SZ / 256), dim3(256), 0, stream, rwp, clp, dg, out);
}

// Round 7
// 160.139 us; speedup vs baseline: 1.2375x; 1.2375x over previous
//
#include <hip/hip_runtime.h>
#include <hip/hip_bf16.h>

typedef unsigned char u8;
typedef unsigned int u32;
typedef float f32x16 __attribute__((ext_vector_type(16)));
typedef int i32x4 __attribute__((ext_vector_type(4)));
typedef int i32x8 __attribute__((ext_vector_type(8)));

#define B_SZ 8192
#define D_SZ 768
#define TAU_INV 10.0f
// values scaled by 16 -> logits scaled by 256; exp2 constant = log2(e)*10/256
#define ESCALE 0.05635527503472513f
#define FP8_SCALE 16.0f

// Tiled operand layout: tile = 32 rows x 64 k-bytes = 2048 B, tiles indexed
// (rowgroup rg = row>>5) * 12 + (kblock kb = k>>6).  Within a tile, byte for
// (row r, k) sits at  half*1024 + h*512 + (r&31)*16 + (k&15)
// where half=(k>>4)&1, h=(k>>5)&1.  Consequence: an MFMA fragment read is
// two perfectly-coalesced dwordx4 at  tile_base + lane*16  (+1024).

// HW packed fp32->fp8(e4m3) conversion: v_cvt_pk_fp8_f32, 2 floats per instr
__device__ __forceinline__ u32 pack_fp8x4(float x, float y, float z, float w) {
    int p = __builtin_amdgcn_cvt_pk_fp8_f32(x, y, 0, false);   // low word
    p = __builtin_amdgcn_cvt_pk_fp8_f32(z, w, p, true);        // high word
    return (u32)p;
}

// ---------------- Kernel 1: row norms, fp8 normalize (x16), tiled store, fp32 diag ----------
__global__ __launch_bounds__(256) void norm_kernel(const float4* __restrict__ v,
                                                   const float4* __restrict__ u,
                                                   u32* __restrict__ vn,
                                                   u32* __restrict__ un,
                                                   float* __restrict__ diag) {
    const int wid = threadIdx.x >> 6, lane = threadIdx.x & 63;
    const int row = blockIdx.x * 4 + wid;
    const float4* vr = v + (size_t)row * 192;
    const float4* ur = u + (size_t)row * 192;
    float4 a[3], b[3];
    float sv = 0.f, su = 0.f, sd = 0.f;
#pragma unroll
    for (int c = 0; c < 3; ++c) {
        a[c] = vr[lane + 64 * c];
        b[c] = ur[lane + 64 * c];
        sv += a[c].x * a[c].x + a[c].y * a[c].y + a[c].z * a[c].z + a[c].w * a[c].w;
        su += b[c].x * b[c].x + b[c].y * b[c].y + b[c].z * b[c].z + b[c].w * b[c].w;
        sd += a[c].x * b[c].x + a[c].y * b[c].y + a[c].z * b[c].z + a[c].w * b[c].w;
    }
#pragma unroll
    for (int m = 1; m < 64; m <<= 1) {
        sv += __shfl_xor(sv, m);
        su += __shfl_xor(su, m);
        sd += __shfl_xor(sd, m);
    }
    const float iv = FP8_SCALE / fmaxf(sqrtf(sv), 1e-8f);
    const float iu = FP8_SCALE / fmaxf(sqrtf(su), 1e-8f);
    const int rg = row >> 5, rr = row & 31;
#pragma unroll
    for (int c = 0; c < 3; ++c) {
        u32 pa = pack_fp8x4(a[c].x * iv, a[c].y * iv, a[c].z * iv, a[c].w * iv);
        u32 pb = pack_fp8x4(b[c].x * iu, b[c].y * iu, b[c].z * iu, b[c].w * iu);
        const int e = lane + 64 * c;   // u32-element index within the row (k = 4e)
        const int idx = (rg * 12 + (e >> 4)) * 512 + ((e >> 2) & 1) * 256 +
                        ((e >> 3) & 1) * 128 + rr * 4 + (e & 3);
        vn[idx] = pa;
        un[idx] = pb;
    }
    if (lane == 0) diag[row] = sd * iv * iu * TAU_INV / (FP8_SCALE * FP8_SCALE);
}

__device__ __forceinline__ i32x8 ldfrag(const u8* p) {
    i32x4 lo = *(const i32x4*)p;
    i32x4 hi = *(const i32x4*)(p + 1024);
    return __builtin_shufflevector(lo, hi, 0, 1, 2, 3, 4, 5, 6, 7);
}

__device__ __forceinline__ f32x16 mx_mfma(i32x8 a, i32x8 b, f32x16 c) {
    return __builtin_amdgcn_mfma_scale_f32_32x32x64_f8f6f4(
        a, b, c, 0, 0, 0, 0x7F7F7F7F, 0, 0x7F7F7F7F);
}

// ------- Kernel 2: 128x128 fp8 MX MFMA tile (BK=64). NO LDS staging, NO K-loop barriers:
//         fragments loaded straight from the pre-tiled global layout (L2-resident),
//         register double-buffered one iteration ahead -------
__global__ __launch_bounds__(256, 3) void simexp_kernel(const u8* __restrict__ vn,
                                                        const u8* __restrict__ un,
                                                        float* __restrict__ rowP,
                                                        float* __restrict__ colP) {
    __shared__ float rowLds[2][128];
    __shared__ float colLds[2][128];

    const int tid  = threadIdx.x;
    const int wid  = tid >> 6;
    const int lane = tid & 63;
    const int l32  = lane & 31;
    const int h    = lane >> 5;
    const int wr = wid >> 1, wc = wid & 1;

    // 8x8 chunked grid for L2 locality
    const int id = blockIdx.x;
    const int chunk = id >> 6;
    const int li = id & 63;
    const int rb = ((chunk >> 3) << 3) + (li >> 3);
    const int cb = ((chunk & 7) << 3) + (li & 7);

    // wave's fragment base pointers (row-group stride = 12 tiles = 24576 B)
    const u8* Aw = vn + (size_t)(rb * 4 + wr * 2) * 24576 + lane * 16;
    const u8* Bw = un + (size_t)(cb * 4 + wc * 2) * 24576 + lane * 16;

    f32x16 acc[2][2];
#pragma unroll
    for (int i = 0; i < 2; ++i)
#pragma unroll
        for (int j = 0; j < 2; ++j)
#pragma unroll
            for (int r = 0; r < 16; ++r) acc[i][j][r] = 0.f;

    i32x8 a0[2], b0[2], a1[2], b1[2];

#define LOADF(t, A, B)                              \
    {                                               \
        A[0] = ldfrag(Aw + (t) * 2048);             \
        A[1] = ldfrag(Aw + 24576 + (t) * 2048);     \
        B[0] = ldfrag(Bw + (t) * 2048);             \
        B[1] = ldfrag(Bw + 24576 + (t) * 2048);     \
    }
#define MFMA4(A, B)                                 \
    {                                               \
        acc[0][0] = mx_mfma(A[0], B[0], acc[0][0]); \
        acc[1][0] = mx_mfma(A[1], B[0], acc[1][0]); \
        acc[0][1] = mx_mfma(A[0], B[1], acc[0][1]); \
        acc[1][1] = mx_mfma(A[1], B[1], acc[1][1]); \
    }

    LOADF(0, a0, b0);
    for (int it = 0; it < 12; it += 2) {
        if (it + 1 < 12) LOADF(it + 1, a1, b1);
        MFMA4(a0, b0);
        if (it + 2 < 12) LOADF(it + 2, a0, b0);
        MFMA4(a1, b1);
    }

    // Epilogue. 32x32 C/D layout: col = lane&31, row = (reg&3) + 8*(reg>>2) + 4*h
    float rowAcc[32];   // [i*16 + reg]
    float colAcc[2];    // [j]
#pragma unroll
    for (int t = 0; t < 32; ++t) rowAcc[t] = 0.f;
    colAcc[0] = 0.f; colAcc[1] = 0.f;
#pragma unroll
    for (int i = 0; i < 2; ++i)
#pragma unroll
        for (int j = 0; j < 2; ++j)
#pragma unroll
            for (int r = 0; r < 16; ++r) {
                float e = exp2f(acc[i][j][r] * ESCALE);
                rowAcc[i * 16 + r] += e;
                colAcc[j] += e;
            }
    // row sums: reduce across the 32 cols (lanes with same h)
#pragma unroll
    for (int m = 1; m < 32; m <<= 1)
#pragma unroll
        for (int t = 0; t < 32; ++t) rowAcc[t] += __shfl_xor(rowAcc[t], m);
    // col sums: add the other h half (rows)
    colAcc[0] += __shfl_xor(colAcc[0], 32);
    colAcc[1] += __shfl_xor(colAcc[1], 32);

    // writers: row (i,reg) written by lanes with l32==reg (one per h)
#pragma unroll
    for (int i = 0; i < 2; ++i)
#pragma unroll
        for (int t = 0; t < 16; ++t)
            if (l32 == t) {
                int row = wr * 64 + i * 32 + (t & 3) + 8 * (t >> 2) + 4 * h;
                rowLds[wc][row] = rowAcc[i * 16 + t];
            }
    if (h == 0) {
#pragma unroll
        for (int j = 0; j < 2; ++j)
            colLds[wr][wc * 64 + j * 32 + l32] = colAcc[j];
    }
    __syncthreads();
    if (tid < 128) {
        rowP[(size_t)cb * B_SZ + rb * 128 + tid] = rowLds[0][tid] + rowLds[1][tid];
    } else {
        const int t = tid - 128;
        colP[(size_t)rb * B_SZ + cb * 128 + t] = colLds[0][t] + colLds[1][t];
    }
}

// ---------------- Kernel 3: reduce partials, log, subtract diag, mean ----------------
__global__ __launch_bounds__(256) void finalize_kernel(const float* __restrict__ rowP,
                                                       const float* __restrict__ colP,
                                                       const float* __restrict__ diag,
                                                       float* __restrict__ out) {
    const int i = blockIdx.x * 256 + threadIdx.x;
    float rs = 0.f, cs = 0.f;
#pragma unroll 8
    for (int p = 0; p < 64; ++p) {
        rs += rowP[(size_t)p * B_SZ + i];
        cs += colP[(size_t)p * B_SZ + i];
    }
    float contrib = (0.75f * logf(rs) + 0.25f * logf(cs) - diag[i]) * (1.0f / (float)B_SZ);
#pragma unroll
    for (int m = 1; m < 64; m <<= 1) contrib += __shfl_xor(contrib, m);
    __shared__ float red[4];
    const int wid = threadIdx.x >> 6, lane = threadIdx.x & 63;
    if (lane == 0) red[wid] = contrib;
    __syncthreads();
    if (threadIdx.x == 0) atomicAdd(out, red[0] + red[1] + red[2] + red[3]);
}

extern "C" void kernel_launch(void* const* d_in, const int* in_sizes, int n_in,
                              void* d_out, int out_size, void* d_ws, size_t ws_size,
                              hipStream_t stream) {
    const float* v = (const float*)d_in[0];
    const float* u = (const float*)d_in[1];
    char* ws = (char*)d_ws;
    // workspace layout (~16.7 MB)
    u8* vn8    = (u8*)(ws);                     // 8192*768    = 6,291,456 (tiled)
    u8* un8    = (u8*)(ws + 6291456);           // 6,291,456 (tiled)
    float* dg  = (float*)(ws + 12582912);       // 8192*4      = 32,768
    float* rwp = (float*)(ws + 12615680);       // 64*8192*4   = 2,097,152
    float* clp = (float*)(ws + 14712832);       // 2,097,152
    float* out = (float*)d_out;

    hipMemsetAsync(out, 0, sizeof(float), stream);
    hipLaunchKernelGGL(norm_kernel, dim3(2048), dim3(256), 0, stream,
                       (const float4*)v, (const float4*)u, (u32*)vn8, (u32*)un8, dg);
    hipLaunchKernelGGL(simexp_kernel, dim3(4096), dim3(256), 0, stream, vn8, un8, rwp, clp);
    hipLaunchKernelGGL(finalize_kernel, dim3(B_SZ / 256), dim3(256), 0, stream, rwp, clp, dg, out);
}